// Round 3
// baseline (240.368 us; speedup 1.0000x reference)
//
#include <hip/hip_runtime.h>
#include <math.h>

#define BB 2
#define SS 2048
#define DD 1024
#define HH 16

typedef unsigned short u16;
using bf16x8 = __attribute__((ext_vector_type(8))) short;   // 8 bf16 in 4 VGPRs
using f32x4  = __attribute__((ext_vector_type(4))) float;   // MFMA accumulator

// ---------------- workspace layout ----------------
// f32: cos[S][32] @ float-offset 0, sin[S][32] @ 65536   (tables)
// u16 region from float-offset 131072:
//   xb   [4096][1024]          bf16 input
//   wtq/wtk/wtv/wto [1024][1024] bf16 transposed weights [n][k]
//   qbuf [B,H,S,64]            bf16, RoPE'd, x0.125
//   kbuf [B,H,S,64]            bf16, RoPE'd
//   vtbuf[B,H,64,S]            bf16, transposed V
//   preb [4096][1024]          bf16 attention output
// total ~48.5 MiB

__device__ __forceinline__ u16 f2bf(float f) {   // round-to-nearest-even
    unsigned u = __float_as_uint(f);
    unsigned r = u + 0x7fffu + ((u >> 16) & 1u);
    return (u16)(r >> 16);
}

// async global->LDS, 16B per lane; LDS dest pattern = wave-uniform base + lane*16
__device__ __forceinline__ void gload_lds16(const void* g, const void* l) {
    __builtin_amdgcn_global_load_lds(
        (const __attribute__((address_space(1))) unsigned int*)(unsigned long long)g,
        (__attribute__((address_space(3))) unsigned int*)(unsigned int)(unsigned long long)l,
        16, 0, 0);
}

// ---------------- 1) RoPE table ----------------
__global__ void rope_table(float* __restrict__ cost, float* __restrict__ sint) {
    int idx = blockIdx.x * 256 + threadIdx.x;   // S*32 = 65536 exact
    int pos = idx >> 5;
    int j   = idx & 31;
    double inv = pow(10000.0, -(double)j / 32.0);
    double ang = (double)pos * inv;
    cost[idx] = (float)cos(ang);
    sint[idx] = (float)sin(ang);
}

// ---------------- 2) x -> bf16 ----------------
__global__ void cvt_x(const float* __restrict__ x, u16* __restrict__ xb) {
    int i = (blockIdx.x * 256 + threadIdx.x) * 4;   // 4096 blocks = 4M exact
    float4 v = *(const float4*)(x + i);
    ushort4 o;
    o.x = f2bf(v.x); o.y = f2bf(v.y); o.z = f2bf(v.z); o.w = f2bf(v.w);
    *(ushort4*)(xb + i) = o;
}

// ---------------- 3) W [K][N] f32 -> Wt [N][K] bf16 ----------------
__global__ void transpose_w(const float* __restrict__ w0, const float* __restrict__ w1,
                            const float* __restrict__ w2, const float* __restrict__ w3,
                            u16* __restrict__ o0, u16* __restrict__ o1,
                            u16* __restrict__ o2, u16* __restrict__ o3) {
    const float* in = (blockIdx.z == 0) ? w0 : (blockIdx.z == 1) ? w1 : (blockIdx.z == 2) ? w2 : w3;
    u16* out        = (blockIdx.z == 0) ? o0 : (blockIdx.z == 1) ? o1 : (blockIdx.z == 2) ? o2 : o3;
    __shared__ float t[32][33];
    int n = blockIdx.x * 32 + threadIdx.x;
    for (int i = threadIdx.y; i < 32; i += 8)
        t[i][threadIdx.x] = in[(size_t)(blockIdx.y * 32 + i) * 1024 + n];
    __syncthreads();
    int k = blockIdx.y * 32 + threadIdx.x;
    for (int i = threadIdx.y; i < 32; i += 8)
        out[(size_t)(blockIdx.x * 32 + i) * 1024 + k] = f2bf(t[threadIdx.x][i]);
}

// ---------------- 4) MFMA GEMM: fused QKV projection + RoPE + layout ----------------
// A = xb [4096][1024], B^T = wt [1024][1024]; m97 structure (128x128 tile, BK=32).
// Q/K: +bias, RoPE, (Q: x0.125), bf16 -> [b,h,s,d]. V: +bias, bf16 -> [b,h,d,s].
__global__ __launch_bounds__(256)
void qkv_gemm(const u16* __restrict__ xb,
              const u16* __restrict__ wtq, const u16* __restrict__ wtk, const u16* __restrict__ wtv,
              const float* __restrict__ bq, const float* __restrict__ bk, const float* __restrict__ bv,
              const float* __restrict__ cost, const float* __restrict__ sint,
              u16* __restrict__ qo, u16* __restrict__ ko, u16* __restrict__ vo)
{
    __shared__ u16 Al[128 * 32];
    __shared__ u16 Bl[128 * 32];

    int bx = blockIdx.x;                 // 24: (which 0..2) x (8 n-tiles)
    int which = bx >> 3;
    int n0 = (bx & 7) << 7;
    int m0 = blockIdx.y << 7;
    const u16*  wt    = (which == 0) ? wtq : (which == 1) ? wtk : wtv;
    const float* bias = (which == 0) ? bq  : (which == 1) ? bk  : bv;

    int t = threadIdx.x;
    int wid = t >> 6, lane = t & 63;
    int wr = wid >> 1, wc = wid & 1;
    int fr = lane & 15, fq = lane >> 4;

    f32x4 acc[4][4];
    #pragma unroll
    for (int m = 0; m < 4; ++m)
        #pragma unroll
        for (int n = 0; n < 4; ++n)
            #pragma unroll
            for (int r = 0; r < 4; ++r) acc[m][n][r] = 0.f;

    int srow = (lane >> 2);
    int skof = (lane & 3) << 3;

    for (int k0 = 0; k0 < 1024; k0 += 32) {
        __syncthreads();
        #pragma unroll
        for (int c = 0; c < 2; ++c) {
            int chunk = wid * 2 + c;
            int row = (chunk << 4) + srow;
            gload_lds16(xb + (size_t)(m0 + row) * 1024 + k0 + skof, &Al[chunk << 9]);
            gload_lds16(wt + (size_t)(n0 + row) * 1024 + k0 + skof, &Bl[chunk << 9]);
        }
        __syncthreads();

        bf16x8 af[4], bf[4];
        #pragma unroll
        for (int m = 0; m < 4; ++m)
            af[m] = *(const bf16x8*)&Al[((wr << 6) + (m << 4) + fr) * 32 + (fq << 3)];
        #pragma unroll
        for (int n = 0; n < 4; ++n)
            bf[n] = *(const bf16x8*)&Bl[((wc << 6) + (n << 4) + fr) * 32 + (fq << 3)];
        #pragma unroll
        for (int m = 0; m < 4; ++m)
            #pragma unroll
            for (int n = 0; n < 4; ++n)
                acc[m][n] = __builtin_amdgcn_mfma_f32_16x16x32_bf16(af[m], bf[n], acc[m][n], 0, 0, 0);
    }

    // C row = m0+wr*64+mm*16+fq*4+j ; C col = n0+wc*64+n*16+fr
    if (which < 2) {
        u16* outp = (which == 0) ? qo : ko;
        const float qs = (which == 0) ? 0.125f : 1.0f;   // 1/sqrt(64), exact in bf16
        #pragma unroll
        for (int n = 0; n < 2; ++n) {                    // d = 16n+fr in [0,32); partner acc n+2
            int col = n0 + (wc << 6) + (n << 4) + fr;
            int h = col >> 6;
            int d = col & 63;
            float b1 = bias[col], b2 = bias[col + 32];
            int a1 = d >> 1;                             // angle index; partner a1+16
            #pragma unroll
            for (int mm = 0; mm < 4; ++mm) {
                #pragma unroll
                for (int j = 0; j < 4; ++j) {
                    int mi = m0 + (wr << 6) + (mm << 4) + (fq << 2) + j;
                    int bi = mi >> 11, s = mi & 2047;
                    float c1 = cost[s * 32 + a1],      s1 = sint[s * 32 + a1];
                    float c2 = cost[s * 32 + a1 + 16], s2 = sint[s * 32 + a1 + 16];
                    float x1 = acc[mm][n][j]     + b1;
                    float x2 = acc[mm][n + 2][j] + b2;
                    size_t base = ((size_t)(bi * HH + h) * SS + s) << 6;
                    outp[base + d]      = f2bf((x1 * c1 - x2 * s1) * qs);
                    outp[base + d + 32] = f2bf((x2 * c2 + x1 * s2) * qs);
                }
            }
        }
    } else {
        #pragma unroll
        for (int n = 0; n < 4; ++n) {
            int col = n0 + (wc << 6) + (n << 4) + fr;
            int h = col >> 6, d = col & 63;
            float bb = bias[col];
            #pragma unroll
            for (int mm = 0; mm < 4; ++mm) {
                #pragma unroll
                for (int j = 0; j < 4; ++j) {
                    int mi = m0 + (wr << 6) + (mm << 4) + (fq << 2) + j;
                    int bi = mi >> 11, s = mi & 2047;
                    vo[((((size_t)(bi * HH + h)) << 6) + d) * SS + s] = f2bf(acc[mm][n][j] + bb);
                }
            }
        }
    }
}

// ---------------- 5) MFMA flash attention ----------------
// grid (32 qblocks, 32 bh), 256 thr. Wave w owns q-rows qb0+w*16..+15.
// Swapped QK^T: S^T acc -> lane holds q=fr, keys 16g+4fq+j. LDS XOR-swizzled.
__global__ __launch_bounds__(256, 4)
void attn(const u16* __restrict__ qb, const u16* __restrict__ kb, const u16* __restrict__ vt,
          const int* __restrict__ mask, u16* __restrict__ preb)
{
    __shared__ u16 Kl[2][4096];   // [64 key][64 d] bf16, swizzled rows (128B)
    __shared__ u16 Vl[2][4096];   // [64 d][64 key] bf16, swizzled
    __shared__ u16 Pl[4][1024];   // per-wave P [16 q][64 key] bf16, swizzled

    const int qb0 = blockIdx.x << 6;
    const int bh  = blockIdx.y;
    const int b   = bh >> 4;
    const int t   = threadIdx.x;
    const int w   = t >> 6;
    const int lane = t & 63;
    const int fr  = lane & 15;
    const int fq  = lane >> 4;
    const int swz = (fr & 7) << 4;

    const char* kbase = (const char*)(kb + ((size_t)bh << 17));
    const char* vbase = (const char*)(vt + ((size_t)bh << 17));
    const int* maskp  = mask + (b << 11);

    // staging: chunk c -> LDS byte c*4096 + t*16 ; row = c*32 + t/8, bo = (t&7)*16
    const int sbo = ((t & 7) << 4) ^ (((t >> 3) & 7) << 4);   // inverse-swizzled src byte

    // Q fragments (RoPE'd, pre-scaled)
    const int qrow = qb0 + (w << 4) + fr;
    const u16* qp = qb + (((size_t)bh << 11) + qrow) * 64 + (fq << 3);
    bf16x8 qf0 = *(const bf16x8*)qp;
    bf16x8 qf1 = *(const bf16x8*)(qp + 32);

    f32x4 o[4];
    #pragma unroll
    for (int n = 0; n < 4; ++n)
        #pragma unroll
        for (int r = 0; r < 4; ++r) o[n][r] = 0.f;
    float mrun = -INFINITY, lrun = 0.f;

    auto STAGE = [&](int buf, int kt) {
        #pragma unroll
        for (int c = 0; c < 2; ++c) {
            int row = (c << 5) + (t >> 3);
            gload_lds16(kbase + ((size_t)(kt << 6) + row) * 128 + sbo,
                        (const char*)&Kl[buf][0] + (c << 12) + t * 16);
            gload_lds16(vbase + (size_t)row * 4096 + (kt << 7) + sbo,
                        (const char*)&Vl[buf][0] + (c << 12) + t * 16);
        }
    };

    STAGE(0, 0);
    __syncthreads();

    for (int kt = 0; kt < 32; ++kt) {
        const int cur = kt & 1;

        float mb[16];
        #pragma unroll
        for (int g = 0; g < 4; ++g)
            #pragma unroll
            for (int j = 0; j < 4; ++j)
                mb[(g << 2) + j] = -1e9f * (float)maskp[(kt << 6) + (g << 4) + (fq << 2) + j];

        if (kt < 31) STAGE(cur ^ 1, kt + 1);

        // QK^T (swapped): sv[g] = S^T for keys 16g..16g+15
        f32x4 sv[4];
        #pragma unroll
        for (int g = 0; g < 4; ++g)
            #pragma unroll
            for (int r = 0; r < 4; ++r) sv[g][r] = 0.f;

        const char* Kb = (const char*)&Kl[cur][0];
        #pragma unroll
        for (int g = 0; g < 4; ++g) {
            int row = (g << 4) + fr;
            bf16x8 kf0 = *(const bf16x8*)(Kb + row * 128 + ((fq << 4) ^ swz));
            bf16x8 kf1 = *(const bf16x8*)(Kb + row * 128 + (((fq << 4) + 64) ^ swz));
            sv[g] = __builtin_amdgcn_mfma_f32_16x16x32_bf16(kf0, qf0, sv[g], 0, 0, 0);
            sv[g] = __builtin_amdgcn_mfma_f32_16x16x32_bf16(kf1, qf1, sv[g], 0, 0, 0);
        }

        // online softmax for q=fr (16 keys in-lane, cross-fq via shfl_xor 16/32)
        float tm = -INFINITY;
        #pragma unroll
        for (int g = 0; g < 4; ++g)
            #pragma unroll
            for (int j = 0; j < 4; ++j) {
                sv[g][j] += mb[(g << 2) + j];
                tm = fmaxf(tm, sv[g][j]);
            }
        tm = fmaxf(tm, __shfl_xor(tm, 16));
        tm = fmaxf(tm, __shfl_xor(tm, 32));
        float newm = fmaxf(mrun, tm);
        float scale = __expf(mrun - newm);   // first tile: exp(-inf)=0
        float ps = 0.f;
        #pragma unroll
        for (int g = 0; g < 4; ++g) {
            float p0 = __expf(sv[g][0] - newm);
            float p1 = __expf(sv[g][1] - newm);
            float p2 = __expf(sv[g][2] - newm);
            float p3 = __expf(sv[g][3] - newm);
            ps += (p0 + p1) + (p2 + p3);
            ushort4 pw;
            pw.x = f2bf(p0); pw.y = f2bf(p1); pw.z = f2bf(p2); pw.w = f2bf(p3);
            // P[q=fr][key=16g+4fq+j] -> swizzled b64 write
            *(ushort4*)((char*)&Pl[w][0] + fr * 128 + (((g << 5) + (fq << 3)) ^ swz)) = pw;
        }
        ps += __shfl_xor(ps, 16);
        ps += __shfl_xor(ps, 32);
        lrun = lrun * scale + ps;
        mrun = newm;

        // rescale O (O rows are q=4*fq+j; fetch that row's scale from lane fr'=4fq+j)
        #pragma unroll
        for (int j = 0; j < 4; ++j) {
            float sj = __shfl(scale, (lane & 48) + (fq << 2) + j);
            #pragma unroll
            for (int n = 0; n < 4; ++n) o[n][j] *= sj;
        }

        // PV: O[q][d] += P[q][k] * V[k][d]
        #pragma unroll
        for (int kk = 0; kk < 2; ++kk) {
            bf16x8 pa = *(const bf16x8*)((const char*)&Pl[w][0] + fr * 128 + (((fq << 4) + (kk << 6)) ^ swz));
            #pragma unroll
            for (int n = 0; n < 4; ++n) {
                int row = (n << 4) + fr;
                bf16x8 vf = *(const bf16x8*)((const char*)&Vl[cur][0] + row * 128 + (((fq << 4) + (kk << 6)) ^ swz));
                o[n] = __builtin_amdgcn_mfma_f32_16x16x32_bf16(pa, vf, o[n], 0, 0, 0);
            }
        }
        __syncthreads();
    }

    // epilogue: lane holds O[q=4fq+j][d=16n+fr]
    #pragma unroll
    for (int j = 0; j < 4; ++j) {
        float lj = __shfl(lrun, (lane & 48) + (fq << 2) + j);
        float inv = 1.0f / lj;
        int qr = qb0 + (w << 4) + (fq << 2) + j;
        u16* op = preb + ((size_t)((b << 11) + qr) << 10) + ((bh & 15) << 6) + fr;
        #pragma unroll
        for (int n = 0; n < 4; ++n)
            op[n << 4] = f2bf(o[n][j] * inv);
    }
}

// ---------------- 6) MFMA GEMM: output projection ----------------
__global__ __launch_bounds__(256)
void out_gemm(const u16* __restrict__ pre, const u16* __restrict__ wto,
              const float* __restrict__ bo, float* __restrict__ outp)
{
    __shared__ u16 Al[128 * 32];
    __shared__ u16 Bl[128 * 32];

    int n0 = blockIdx.x << 7;   // 8 tiles
    int m0 = blockIdx.y << 7;   // 32 tiles

    int t = threadIdx.x;
    int wid = t >> 6, lane = t & 63;
    int wr = wid >> 1, wc = wid & 1;
    int fr = lane & 15, fq = lane >> 4;

    f32x4 acc[4][4];
    #pragma unroll
    for (int m = 0; m < 4; ++m)
        #pragma unroll
        for (int n = 0; n < 4; ++n)
            #pragma unroll
            for (int r = 0; r < 4; ++r) acc[m][n][r] = 0.f;

    int srow = (lane >> 2);
    int skof = (lane & 3) << 3;

    for (int k0 = 0; k0 < 1024; k0 += 32) {
        __syncthreads();
        #pragma unroll
        for (int c = 0; c < 2; ++c) {
            int chunk = wid * 2 + c;
            int row = (chunk << 4) + srow;
            gload_lds16(pre + (size_t)(m0 + row) * 1024 + k0 + skof, &Al[chunk << 9]);
            gload_lds16(wto + (size_t)(n0 + row) * 1024 + k0 + skof, &Bl[chunk << 9]);
        }
        __syncthreads();

        bf16x8 af[4], bf[4];
        #pragma unroll
        for (int m = 0; m < 4; ++m)
            af[m] = *(const bf16x8*)&Al[((wr << 6) + (m << 4) + fr) * 32 + (fq << 3)];
        #pragma unroll
        for (int n = 0; n < 4; ++n)
            bf[n] = *(const bf16x8*)&Bl[((wc << 6) + (n << 4) + fr) * 32 + (fq << 3)];
        #pragma unroll
        for (int m = 0; m < 4; ++m)
            #pragma unroll
            for (int n = 0; n < 4; ++n)
                acc[m][n] = __builtin_amdgcn_mfma_f32_16x16x32_bf16(af[m], bf[n], acc[m][n], 0, 0, 0);
    }

    #pragma unroll
    for (int n = 0; n < 4; ++n) {
        int col = n0 + (wc << 6) + (n << 4) + fr;
        float bb = bo[col];
        #pragma unroll
        for (int m = 0; m < 4; ++m) {
            #pragma unroll
            for (int j = 0; j < 4; ++j) {
                int mi = m0 + (wr << 6) + (m << 4) + (fq << 2) + j;
                outp[(size_t)mi * 1024 + col] = acc[m][n][j] + bb;
            }
        }
    }
}

// ---------------- launch ----------------
extern "C" void kernel_launch(void* const* d_in, const int* in_sizes, int n_in,
                              void* d_out, int out_size, void* d_ws, size_t ws_size,
                              hipStream_t stream) {
    const float* x    = (const float*)d_in[0];
    const int*   mask = (const int*)  d_in[1];
    const float* wq   = (const float*)d_in[2];
    const float* bq   = (const float*)d_in[3];
    const float* wk   = (const float*)d_in[4];
    const float* bk   = (const float*)d_in[5];
    const float* wv   = (const float*)d_in[6];
    const float* bv   = (const float*)d_in[7];
    const float* wo   = (const float*)d_in[8];
    const float* bo   = (const float*)d_in[9];
    float* out = (float*)d_out;
    float* ws  = (float*)d_ws;

    float* cosT = ws;
    float* sinT = ws + 65536;
    u16* xb    = (u16*)(ws + 131072);
    u16* wtq   = xb    + 4194304;
    u16* wtk   = wtq   + 1048576;
    u16* wtv   = wtk   + 1048576;
    u16* wto   = wtv   + 1048576;
    u16* qbuf  = wto   + 1048576;
    u16* kbuf  = qbuf  + 4194304;
    u16* vtbuf = kbuf  + 4194304;
    u16* preb  = vtbuf + 4194304;

    hipLaunchKernelGGL(rope_table, dim3(256), dim3(256), 0, stream, cosT, sinT);
    hipLaunchKernelGGL(cvt_x, dim3(4096), dim3(256), 0, stream, x, xb);
    hipLaunchKernelGGL(transpose_w, dim3(32, 32, 4), dim3(32, 8), 0, stream,
                       wq, wk, wv, wo, wtq, wtk, wtv, wto);
    hipLaunchKernelGGL(qkv_gemm, dim3(24, 32), dim3(256), 0, stream,
                       xb, wtq, wtk, wtv, bq, bk, bv, cosT, sinT, qbuf, kbuf, vtbuf);
    hipLaunchKernelGGL(attn, dim3(32, 32), dim3(256), 0, stream,
                       qbuf, kbuf, vtbuf, mask, preb);
    hipLaunchKernelGGL(out_gemm, dim3(8, 32), dim3(256), 0, stream, preb, wto, bo, out);
}